// Round 6
// baseline (220.634 us; speedup 1.0000x reference)
//
#include <hip/hip_runtime.h>
#include <hip/hip_fp16.h>

#define N_ANG 256
#define N_BATCH 8
#define STRIDE 259                   // texture entries per row (u = 0..258)
#define MAXR 35                      // nE+2 <= 35 rows

#if defined(__has_builtin)
#  if __has_builtin(__builtin_amdgcn_fdot2)
#    define HAVE_FDOT2 1
#  endif
#endif

// Eighth-image "all-taps" texture (2 blocks/CU):
//   entry (t,u): dw0 = half2(img[rT][cL], img[rT][cR])   (TL, TR)
//               dw1 = half2(img[rB][cL], img[rB][cR])   (BL, BR)
//   rT = prLo+t-2, rB = rT+1, cL = u-2, cR = u-1; zeros outside the image,
//   and rows t=0 / t=nE+1 and cols u=0 / u=258 are all-zero guards.
// A bilinear sample (pr=floor(Yp), cp=floor(Xp)) needs ONE ds_read_b64 at
// idx = (pr-prLo+1)*259 + cp+1 : no perms, hfma2 vertical lerp directly.
// 8 pr-partition blocks accumulate each ray via atomicAdd; closed-form fma
// coords are bit-identical across blocks -> exactly-once sample ownership.
__global__ __launch_bounds__(1024, 8) void radon_e8(const float* __restrict__ x,
                                                    const float* __restrict__ angles,
                                                    float* __restrict__ out) {
    __shared__ uint2 S[MAXR * STRIDE];   // 9065 * 8B = 72,520 B

    int bid  = blockIdx.x;
    int b    = bid & 7;              // batch (XCD-resident image)
    int rest = bid >> 3;
    int agrp = rest & 63;            // 4 angles per block
    int q    = rest >> 6;            // eighth 0..7
    int prLo = q ? (33 + 32 * (q - 1)) : 0;   // owns pr in [prLo, prLo+nE)
    int nE   = q ? 32 : 33;
    int tid  = threadIdx.x;

    // ---- stage all-taps texture for this eighth
    const float* im = x + (size_t)b * 65536;
    int nEnt = (nE + 2) * STRIDE;
    for (int idx = tid; idx < nEnt; idx += 1024) {
        int t = idx / STRIDE;
        int u = idx - t * STRIDE;
        int rT = prLo + t - 2, rB = rT + 1;
        int cL = u - 2,        cR = u - 1;
        bool real = (t >= 1) & (t <= nE) & (u >= 1) & (u <= 257);
        bool okT = (unsigned)rT < 256u, okB = (unsigned)rB < 256u;
        bool okL = real & ((unsigned)cL < 256u);
        bool okR = real & ((unsigned)cR < 256u);
        float vTL = (okL && okT) ? im[rT * 256 + cL] : 0.0f;
        float vTR = (okR && okT) ? im[rT * 256 + cR] : 0.0f;
        float vBL = (okL && okB) ? im[rB * 256 + cL] : 0.0f;
        float vBR = (okR && okB) ? im[rB * 256 + cR] : 0.0f;
        __half2 d0 = __floats2half2_rn(vTL, vTR);
        __half2 d1 = __floats2half2_rn(vBL, vBR);
        S[idx] = make_uint2(*reinterpret_cast<uint32_t*>(&d0),
                            *reinterpret_cast<uint32_t*>(&d1));
    }
    __syncthreads();

    // ---- ray setup: Xp = Xb - sf*sn, Yp = Yb + sf*cs (padded coords = ref+1)
    int d = tid & 255;
    int a = agrp * 4 + (tid >> 8);
    float ang = angles[a];
    float sn = sinf(ang), cs = cosf(ang);
    float td = (float)d - 127.5f;
    float Xb = fmaf(td, cs, 128.5f);
    float Yb = fmaf(td, sn, 128.5f);

    // per-lane sf window with 0.9-margin crossings (guard rows/cols absorb slop)
    float lo = -127.5f, hi = 127.5f;
    float yL = (float)prLo - 0.9f, yH = (float)(prLo + nE) + 0.9f;
    if (fabsf(cs) > 1e-6f) {
        float r = 1.0f / cs;
        float p = (yL - Yb) * r, q2 = (yH - Yb) * r;
        lo = fmaxf(lo, fminf(p, q2)); hi = fminf(hi, fmaxf(p, q2));
    } else if (!(Yb > yL + 0.4f && Yb < yH - 0.4f)) { lo = 1.0f; hi = 0.0f; }
    if (fabsf(sn) > 1e-6f) {
        float r = -1.0f / sn;
        float p = (-0.9f - Xb) * r, q2 = (257.9f - Xb) * r;
        lo = fmaxf(lo, fminf(p, q2)); hi = fminf(hi, fmaxf(p, q2));
    } else if (!(Xb > -0.4f && Xb < 257.4f)) { lo = 1.0f; hi = 0.0f; }
    int siLo = max(0,   (int)ceilf(lo + 127.5f));
    int siHi = min(255, (int)floorf(hi + 127.5f));

    int KOFF = (1 - prLo) * STRIDE + 1;   // folds (t = pr-prLo+1, u = cp+1)

    // ---- main loop: 1 ds_read_b64 + ~18 VALU per sample
    float acc = 0.0f;
    float sf = (float)siLo - 127.5f;
    #pragma unroll 8
    for (int si = siLo; si <= siHi; ++si) {
        float Xp = fmaf(sf, -sn, Xb);
        float Yp = fmaf(sf,  cs, Yb);
        float fx = floorf(Xp), fy = floorf(Yp);
        float wx = Xp - fx, wy = Yp - fy;
        int idx = (int)fy * STRIDE + (int)fx + KOFF;
        uint2 V = S[idx];                                   // ds_read_b64
        __half2 Ph = *reinterpret_cast<__half2*>(&V.x);     // (TL, TR)
        __half2 Qh = *reinterpret_cast<__half2*>(&V.y);     // (BL, BR)
        __half2 wy2 = __float2half2_rn(wy);
        __half2 Rh = __hfma2(wy2, __hsub2(Qh, Ph), Ph);     // vertical lerp
#ifdef HAVE_FDOT2
        __half2 W = __floats2half2_rn(1.0f - wx, wx);
        acc = __builtin_amdgcn_fdot2(Rh, W, acc, false);    // horizontal lerp
#else
        float r0 = __low2float(Rh), r1 = __high2float(Rh);
        acc += fmaf(wx, r1 - r0, r0);
#endif
        sf += 1.0f;
    }
    unsafeAtomicAdd(&out[((size_t)b * N_ANG + a) * 256 + d], acc);
}

extern "C" void kernel_launch(void* const* d_in, const int* in_sizes, int n_in,
                              void* d_out, int out_size, void* d_ws, size_t ws_size,
                              hipStream_t stream) {
    const float* x      = (const float*)d_in[0];
    const float* angles = (const float*)d_in[1];
    float* out = (float*)d_out;
    hipMemsetAsync(out, 0, (size_t)out_size * sizeof(float), stream);
    // 4096 blocks = 8 batches x 64 angle-groups x 8 eighths; batch = blockIdx%8
    radon_e8<<<N_BATCH * (N_ANG / 4) * 8, 1024, 0, stream>>>(x, angles, out);
}

// Round 7
// 185.022 us; speedup vs baseline: 1.1925x; 1.1925x over previous
//
#include <hip/hip_runtime.h>
#include <hip/hip_fp16.h>

#define N_ANG 256
#define N_BATCH 8
#define STRIDE 261                  // dword row stride (260 cols used + 1 pad)
#define MAXROWS 67                  // nE+2 <= 67

#if defined(__has_builtin)
#  if __has_builtin(__builtin_amdgcn_fdot2)
#    define HAVE_FDOT2 1
#  endif
#endif

// R4 structure (best so far): quarter-image overlapping-pair texture,
// 2 blocks/CU. This round adds hand-staged 8-deep load batching so each
// wave keeps 8 independent ds_read2_b32 in flight (the compiler alone
// reuses data regs and serializes), plus dual accumulators.
__global__ __launch_bounds__(1024, 8) void radon_q8(const float* __restrict__ x,
                                                    const float* __restrict__ angles,
                                                    float* __restrict__ out) {
    __shared__ uint32_t S[MAXROWS * STRIDE];   // 17,487 dw = 69,948 B

    int bid  = blockIdx.x;
    int b    = bid & 7;              // batch (XCD-resident image)
    int rest = bid >> 3;
    int agrp = rest & 63;            // 4 angles per block
    int qq   = rest >> 6;            // quarter 0..3
    int prLo = (qq == 0) ? 0 : (qq * 64 + 1);
    int nE   = (qq == 0) ? 65 : 64;
    int tid  = threadIdx.x;

    // ---- stage texture: T[t][u] = half2(img[prLo+t-2][u-2], img[prLo+t-1][u-2])
    // rows t=0, t=nE+1 and cols u<2-pad are zero guards.
    const float* im = x + (size_t)b * 65536;
    int nEnt = (nE + 2) * STRIDE;
    for (int idx = tid; idx < nEnt; idx += 1024) {
        int t = idx / STRIDE;
        int u = idx - t * STRIDE;
        int c = u - 2;
        int rT = prLo + t - 2, rB = rT + 1;
        bool real = (t >= 1) & (t <= nE) & ((unsigned)c < 256u);
        float vT = (real && (unsigned)rT < 256u) ? im[rT * 256 + c] : 0.0f;
        float vB = (real && (unsigned)rB < 256u) ? im[rB * 256 + c] : 0.0f;
        __half2 hv = __floats2half2_rn(vT, vB);
        S[idx] = *reinterpret_cast<const uint32_t*>(&hv);
    }
    __syncthreads();

    // ---- ray setup: Xp = Xb - sf*sn, Yp = Yb + sf*cs (padded coords = ref+1)
    int d = tid & 255;
    int a = agrp * 4 + (tid >> 8);
    float ang = angles[a];
    float sn = sinf(ang), cs = cosf(ang);
    float td = (float)d - 127.5f;
    float Xb = fmaf(td, cs, 128.5f);
    float Yb = fmaf(td, sn, 128.5f);

    // per-lane sf window, 0.9-margin crossings (guards absorb float slop)
    float lo = -127.5f, hi = 127.5f;
    float yL = (float)prLo - 0.9f, yH = (float)(prLo + nE) + 0.9f;
    if (fabsf(cs) > 1e-6f) {
        float r = 1.0f / cs;
        float p = (yL - Yb) * r, q2 = (yH - Yb) * r;
        lo = fmaxf(lo, fminf(p, q2)); hi = fminf(hi, fmaxf(p, q2));
    } else if (!(Yb > yL + 0.4f && Yb < yH - 0.4f)) { lo = 1.0f; hi = 0.0f; }
    if (fabsf(sn) > 1e-6f) {
        float r = -1.0f / sn;
        float p = (-0.9f - Xb) * r, q2 = (257.9f - Xb) * r;
        lo = fmaxf(lo, fminf(p, q2)); hi = fminf(hi, fmaxf(p, q2));
    } else if (!(Xb > -0.4f && Xb < 257.4f)) { lo = 1.0f; hi = 0.0f; }
    int siLo = max(0,   (int)ceilf(lo + 127.5f));
    int siHi = min(255, (int)floorf(hi + 127.5f));

    int KOFF = (1 - prLo) * STRIDE + 1;

    // ---- main loop: chunks of 8, loads batched for MLP, dual accumulators
    float acc0 = 0.0f, acc1 = 0.0f;
    int si = siLo;
    for (; si + 7 <= siHi; si += 8) {
        float sfb = (float)si - 127.5f;
        int   idx[8];
        float wxa[8], wya[8];
        #pragma unroll
        for (int j = 0; j < 8; ++j) {
            float sfj = sfb + (float)j;
            float Xp = fmaf(sfj, -sn, Xb);
            float Yp = fmaf(sfj,  cs, Yb);
            float fx = floorf(Xp), fy = floorf(Yp);
            wxa[j] = Xp - fx;
            wya[j] = Yp - fy;
            idx[j] = (int)fy * STRIDE + (int)fx + KOFF;
        }
        uint32_t A0[8], A1[8];
        #pragma unroll
        for (int j = 0; j < 8; ++j) {   // 16 ds_read dwords issued back-to-back
            A0[j] = S[idx[j]];
            A1[j] = S[idx[j] + 1];
        }
        #pragma unroll
        for (int j = 0; j < 8; ++j) {
            uint32_t Pu = __builtin_amdgcn_perm(A1[j], A0[j], 0x05040100u); // (TL,TR)
            uint32_t Qu = __builtin_amdgcn_perm(A1[j], A0[j], 0x07060302u); // (BL,BR)
            __half2 Ph = *reinterpret_cast<__half2*>(&Pu);
            __half2 Qh = *reinterpret_cast<__half2*>(&Qu);
            __half2 wy2 = __float2half2_rn(wya[j]);
            __half2 Rh = __hfma2(wy2, __hsub2(Qh, Ph), Ph);
#ifdef HAVE_FDOT2
            __half2 W = __floats2half2_rn(1.0f - wxa[j], wxa[j]);
            if (j & 1) acc1 = __builtin_amdgcn_fdot2(Rh, W, acc1, false);
            else       acc0 = __builtin_amdgcn_fdot2(Rh, W, acc0, false);
#else
            float r0 = __low2float(Rh), r1 = __high2float(Rh);
            float v = fmaf(wxa[j], r1 - r0, r0);
            if (j & 1) acc1 += v; else acc0 += v;
#endif
        }
    }
    for (; si <= siHi; ++si) {          // tail
        float sfj = (float)si - 127.5f;
        float Xp = fmaf(sfj, -sn, Xb);
        float Yp = fmaf(sfj,  cs, Yb);
        float fx = floorf(Xp), fy = floorf(Yp);
        float wx = Xp - fx, wy = Yp - fy;
        int idx = (int)fy * STRIDE + (int)fx + KOFF;
        uint32_t A0 = S[idx], A1 = S[idx + 1];
        uint32_t Pu = __builtin_amdgcn_perm(A1, A0, 0x05040100u);
        uint32_t Qu = __builtin_amdgcn_perm(A1, A0, 0x07060302u);
        __half2 Ph = *reinterpret_cast<__half2*>(&Pu);
        __half2 Qh = *reinterpret_cast<__half2*>(&Qu);
        __half2 wy2 = __float2half2_rn(wy);
        __half2 Rh = __hfma2(wy2, __hsub2(Qh, Ph), Ph);
#ifdef HAVE_FDOT2
        __half2 W = __floats2half2_rn(1.0f - wx, wx);
        acc0 = __builtin_amdgcn_fdot2(Rh, W, acc0, false);
#else
        float r0 = __low2float(Rh), r1 = __high2float(Rh);
        acc0 += fmaf(wx, r1 - r0, r0);
#endif
    }
    if (siLo <= siHi)
        unsafeAtomicAdd(&out[((size_t)b * N_ANG + a) * 256 + d], acc0 + acc1);
}

extern "C" void kernel_launch(void* const* d_in, const int* in_sizes, int n_in,
                              void* d_out, int out_size, void* d_ws, size_t ws_size,
                              hipStream_t stream) {
    const float* x      = (const float*)d_in[0];
    const float* angles = (const float*)d_in[1];
    float* out = (float*)d_out;
    hipMemsetAsync(out, 0, (size_t)out_size * sizeof(float), stream);
    // 2048 blocks = 8 batches x 64 angle-groups x 4 quarters; batch = blockIdx%8
    radon_q8<<<N_BATCH * (N_ANG / 4) * 4, 1024, 0, stream>>>(x, angles, out);
}

// Round 8
// 125.914 us; speedup vs baseline: 1.7523x; 1.4694x over previous
//
#include <hip/hip_runtime.h>
#include <hip/hip_fp16.h>

#define N_ANG 256
#define N_BATCH 8
#define STRIDE 261                  // dword row stride (259 used + 2 pad)
#define MAXROWS 67                  // nE+2 <= 67

#if defined(__has_builtin)
#  if __has_builtin(__builtin_amdgcn_fdot2)
#    define HAVE_FDOT2 1
#  endif
#endif

// R4 structure + per-angle-group adaptive band axis.
// Effective image E = img (normal, |cs|>=|sn|) or img^T (swapped).
// Quarter bands over E's rows; texture T[t][u] = half2(E[prLo+t-2][u-2],
// E[prLo+t-1][u-2]) with zero guards at t=0, t=nE+1 and u<2 / u>257.
// Sample (R,C) in E-coords: one ds_read2_b32 at idx=floor(R)*261+floor(C)+KOFF
// gives all 4 taps. Band slope dR = max(|sn|,|cs|) >= 0.707 -> short windows,
// no masked-lane waste. Axis choice is group-uniform so the 4 quarter-blocks
// compute bit-identical (R,C) -> exactly-once sample ownership (guard rows
// absorb float-margin slop).
__global__ __launch_bounds__(1024, 8) void radon_qa(const float* __restrict__ x,
                                                    const float* __restrict__ angles,
                                                    float* __restrict__ out) {
    __shared__ uint32_t S[MAXROWS * STRIDE];   // 17,487 dw = 69,948 B

    int bid  = blockIdx.x;
    int b    = bid & 7;              // batch (XCD-resident image)
    int rest = bid >> 3;
    int agrp = rest & 63;            // 4 angles per block
    int qq   = rest >> 6;            // quarter 0..3
    int prLo = (qq == 0) ? 0 : (qq * 64 + 1);
    int nE   = (qq == 0) ? 65 : 64;
    int tid  = threadIdx.x;

    // group-uniform axis choice (same for all 4 quarter-blocks of this agrp)
    float angRep = 0.5f * (angles[agrp * 4 + 1] + angles[agrp * 4 + 2]);
    bool swapped = fabsf(sinf(angRep)) > fabsf(cosf(angRep));

    const float* im = x + (size_t)b * 65536;
    int TT = nE + 2;
    int nEnt = TT * STRIDE;
    if (!swapped) {
        // row bands: consecutive threads -> consecutive u -> coalesced row reads
        for (int idx = tid; idx < nEnt; idx += 1024) {
            int t = idx / STRIDE;
            int u = idx - t * STRIDE;
            int c = u - 2;
            int rT = prLo + t - 2, rB = rT + 1;
            bool real = (t >= 1) & (t <= nE) & ((unsigned)c < 256u);
            float vT = (real && (unsigned)rT < 256u) ? im[rT * 256 + c] : 0.0f;
            float vB = (real && (unsigned)rB < 256u) ? im[rB * 256 + c] : 0.0f;
            __half2 hv = __floats2half2_rn(vT, vB);
            S[idx] = *reinterpret_cast<const uint32_t*>(&hv);
        }
    } else {
        // col bands: E[r'][c'] = img[c'][r']; iterate t fastest so consecutive
        // threads read consecutive image cols (coalesced); LDS write stride
        // 261 dw = 5 mod 32 banks -> conflict-free.
        for (int e = tid; e < nEnt; e += 1024) {
            int u = e / TT;
            int t = e - u * TT;
            int c = u - 2;                        // image row
            int rT = prLo + t - 2, rB = rT + 1;   // image cols
            bool real = (t >= 1) & (t <= nE) & ((unsigned)c < 256u);
            float vT = (real && (unsigned)rT < 256u) ? im[c * 256 + rT] : 0.0f;
            float vB = (real && (unsigned)rB < 256u) ? im[c * 256 + rB] : 0.0f;
            __half2 hv = __floats2half2_rn(vT, vB);
            S[t * STRIDE + u] = *reinterpret_cast<const uint32_t*>(&hv);
        }
    }
    __syncthreads();

    // ---- ray setup (padded coords = ref+1): Xp = Xb - sf*sn, Yp = Yb + sf*cs
    int d = tid & 255;
    int a = agrp * 4 + (tid >> 8);
    float ang = angles[a];
    float sn = sinf(ang), cs = cosf(ang);
    float td = (float)d - 127.5f;
    float Xb = fmaf(td, cs, 128.5f);
    float Yb = fmaf(td, sn, 128.5f);
    // generic band coords: R = band axis (|dR| >= 0.707), C = cross axis
    float Rb, dR, Cb, dC;
    if (!swapped) { Rb = Yb; dR = cs;  Cb = Xb; dC = -sn; }
    else          { Rb = Xb; dR = -sn; Cb = Yb; dC = cs;  }

    // per-lane sf window, 0.9-margin crossings (guards absorb float slop)
    float lo = -127.5f, hi = 127.5f;
    float yL = (float)prLo - 0.9f, yH = (float)(prLo + nE) + 0.9f;
    {   // band axis: |dR| >= 0.7, never degenerate
        float r = 1.0f / dR;
        float p = (yL - Rb) * r, q2 = (yH - Rb) * r;
        lo = fmaxf(lo, fminf(p, q2)); hi = fminf(hi, fmaxf(p, q2));
    }
    if (fabsf(dC) > 1e-6f) {
        float r = 1.0f / dC;
        float p = (-0.9f - Cb) * r, q2 = (257.9f - Cb) * r;
        lo = fmaxf(lo, fminf(p, q2)); hi = fminf(hi, fmaxf(p, q2));
    } else if (!(Cb > -0.4f && Cb < 257.4f)) { lo = 1.0f; hi = 0.0f; }
    int siLo = max(0,   (int)ceilf(lo + 127.5f));
    int siHi = min(255, (int)floorf(hi + 127.5f));

    int KOFF = (1 - prLo) * STRIDE + 1;   // folds (t = pr-prLo+1, u = cp+1)

    // ---- main loop: 1 ds_read2_b32 + ~20 VALU per sample
    float acc = 0.0f;
    float sf = (float)siLo - 127.5f;
    #pragma unroll 4
    for (int si = siLo; si <= siHi; ++si) {
        float Rp = fmaf(sf, dR, Rb);
        float Cp = fmaf(sf, dC, Cb);
        float fr = floorf(Rp), fc = floorf(Cp);
        float wr = Rp - fr, wc = Cp - fc;
        int idx = (int)fr * STRIDE + (int)fc + KOFF;
        uint32_t A0 = S[idx], A1 = S[idx + 1];                     // ds_read2_b32
        uint32_t Pu = __builtin_amdgcn_perm(A1, A0, 0x05040100u);  // (TL, TR)
        uint32_t Qu = __builtin_amdgcn_perm(A1, A0, 0x07060302u);  // (BL, BR)
        __half2 Ph = *reinterpret_cast<__half2*>(&Pu);
        __half2 Qh = *reinterpret_cast<__half2*>(&Qu);
        __half2 wr2 = __float2half2_rn(wr);
        __half2 Rh = __hfma2(wr2, __hsub2(Qh, Ph), Ph);            // band-axis lerp
#ifdef HAVE_FDOT2
        __half2 W = __floats2half2_rn(1.0f - wc, wc);
        acc = __builtin_amdgcn_fdot2(Rh, W, acc, false);           // cross-axis lerp
#else
        float r0 = __low2float(Rh), r1 = __high2float(Rh);
        acc += fmaf(wc, r1 - r0, r0);
#endif
        sf += 1.0f;
    }
    if (siLo <= siHi)
        unsafeAtomicAdd(&out[((size_t)b * N_ANG + a) * 256 + d], acc);
}

extern "C" void kernel_launch(void* const* d_in, const int* in_sizes, int n_in,
                              void* d_out, int out_size, void* d_ws, size_t ws_size,
                              hipStream_t stream) {
    const float* x      = (const float*)d_in[0];
    const float* angles = (const float*)d_in[1];
    float* out = (float*)d_out;
    hipMemsetAsync(out, 0, (size_t)out_size * sizeof(float), stream);
    // 2048 blocks = 8 batches x 64 angle-groups x 4 quarters; batch = blockIdx%8
    radon_qa<<<N_BATCH * (N_ANG / 4) * 4, 1024, 0, stream>>>(x, angles, out);
}

// Round 10
// 118.284 us; speedup vs baseline: 1.8653x; 1.0645x over previous
//
#include <hip/hip_runtime.h>
#include <hip/hip_fp16.h>

#define N_ANG 256
#define N_BATCH 8
#define STRIDE 261                  // dword row stride (259 used + 2 pad)
#define MAXROWS 67                  // nE+2 <= 67

#if defined(__has_builtin)
#  if __has_builtin(__builtin_amdgcn_fdot2) && __has_builtin(__builtin_amdgcn_cvt_pkrtz)
#    define HAVE_FDOT2 1
#  endif
#endif

typedef __fp16 fp16x2 __attribute__((ext_vector_type(2)));   // builtin's native type
typedef _Float16 h2 __attribute__((ext_vector_type(2)));

// R7 structure (adaptive band axis, quarter bands, overlapping-pair texture,
// 2 blocks/CU) + instruction diet:
//  - vertical lerp via v_dot2_f32_f16 on the (top,bot) texture dword directly
//    (kills 2 v_perm + pk ops), horizontal lerp in f32, dual accumulators
//  - v_cvt_pkrtz for the weight pack (1 instr vs RN expansion)
//  - byte-address mad (fr*1044 + fc*4 + KOFFB)
//  - setup: v_rcp instead of precise divides, 0.25-sample window margins
__global__ __launch_bounds__(1024, 8) void radon_d(const float* __restrict__ x,
                                                   const float* __restrict__ angles,
                                                   float* __restrict__ out) {
    __shared__ uint32_t S[MAXROWS * STRIDE];   // 17,487 dw = 69,948 B

    int bid  = blockIdx.x;
    int b    = bid & 7;              // batch (XCD-resident image)
    int rest = bid >> 3;
    int agrp = rest & 63;            // 4 angles per block
    int qq   = rest >> 6;            // quarter 0..3
    int prLo = (qq == 0) ? 0 : (qq * 64 + 1);
    int nE   = (qq == 0) ? 65 : 64;
    int tid  = threadIdx.x;

    // group-uniform axis choice (same for all 4 quarter-blocks of this agrp)
    float angRep = 0.5f * (angles[agrp * 4 + 1] + angles[agrp * 4 + 2]);
    bool swapped = fabsf(sinf(angRep)) > fabsf(cosf(angRep));

    const float* im = x + (size_t)b * 65536;
    int TT = nE + 2;
    int nEnt = TT * STRIDE;
    if (!swapped) {
        // row bands: consecutive threads -> consecutive u -> coalesced reads
        for (int idx = tid; idx < nEnt; idx += 1024) {
            int t = idx / STRIDE;
            int u = idx - t * STRIDE;
            int c = u - 2;
            int rT = prLo + t - 2, rB = rT + 1;
            bool real = (t >= 1) & (t <= nE) & ((unsigned)c < 256u);
            float vT = (real && (unsigned)rT < 256u) ? im[rT * 256 + c] : 0.0f;
            float vB = (real && (unsigned)rB < 256u) ? im[rB * 256 + c] : 0.0f;
            __half2 hv = __floats2half2_rn(vT, vB);
            S[idx] = *reinterpret_cast<const uint32_t*>(&hv);
        }
    } else {
        // col bands: E[r'][c'] = img[c'][r']; t fastest -> coalesced global,
        // LDS write stride 261 dw = 5 mod 32 banks -> conflict-free.
        for (int e = tid; e < nEnt; e += 1024) {
            int u = e / TT;
            int t = e - u * TT;
            int c = u - 2;                        // image row
            int rT = prLo + t - 2, rB = rT + 1;   // image cols
            bool real = (t >= 1) & (t <= nE) & ((unsigned)c < 256u);
            float vT = (real && (unsigned)rT < 256u) ? im[c * 256 + rT] : 0.0f;
            float vB = (real && (unsigned)rB < 256u) ? im[c * 256 + rB] : 0.0f;
            __half2 hv = __floats2half2_rn(vT, vB);
            S[t * STRIDE + u] = *reinterpret_cast<const uint32_t*>(&hv);
        }
    }
    __syncthreads();

    // ---- ray setup (padded coords = ref+1): Xp = Xb - sf*sn, Yp = Yb + sf*cs
    int d = tid & 255;
    int a = agrp * 4 + (tid >> 8);
    float ang = angles[a];
    float sn = sinf(ang), cs = cosf(ang);
    float td = (float)d - 127.5f;
    float Xb = fmaf(td, cs, 128.5f);
    float Yb = fmaf(td, sn, 128.5f);
    // band coords: R = band axis (|dR| >= 0.707), C = cross axis
    float Rb, dR, Cb, dC;
    if (!swapped) { Rb = Yb; dR = cs;  Cb = Xb; dC = -sn; }
    else          { Rb = Xb; dR = -sn; Cb = Yb; dC = cs;  }

    // per-lane sf window, 0.25-margin crossings via v_rcp (guards absorb slop).
    // Valid samples: Rp in [prLo, prLo+nE), Cp in [0, 257). Degenerate dC -> 0
    // only near axis angles where Cb is always in-range, so rcp(+-0)=+-inf
    // yields a full (correct) window; |dR| >= 0.707 is never degenerate.
    float lo = -127.5f, hi = 127.5f;
    {
        float r = __builtin_amdgcn_rcpf(dR);
        float p = ((float)prLo - 0.25f - Rb) * r;
        float q2 = ((float)(prLo + nE) + 0.25f - Rb) * r;
        lo = fmaxf(lo, fminf(p, q2)); hi = fminf(hi, fmaxf(p, q2));
    }
    {
        float r = __builtin_amdgcn_rcpf(dC);
        float p = (-0.25f - Cb) * r;
        float q2 = (257.25f - Cb) * r;
        lo = fmaxf(lo, fminf(p, q2)); hi = fminf(hi, fmaxf(p, q2));
    }
    int siLo = max(0,   (int)ceilf(lo + 127.5f));
    int siHi = min(255, (int)floorf(hi + 127.5f));

    int KOFFB = ((1 - prLo) * STRIDE + 1) * 4;   // byte offset fold

    // ---- main loop: 1 ds_read2_b32 + ~17 VALU per sample
    float accB = 0.0f, accD = 0.0f;
    float sf = (float)siLo - 127.5f;
    #pragma unroll 4
    for (int si = siLo; si <= siHi; ++si) {
        float Rp = fmaf(sf, dR, Rb);
        float Cp = fmaf(sf, dC, Cb);
        sf += 1.0f;
        float fr = floorf(Rp), fc = floorf(Cp);
        float wr = Rp - fr, wc = Cp - fc;
        int baddr = (int)fr * (STRIDE * 4) + (int)fc * 4 + KOFFB;
        uint32_t A0 = *(const uint32_t*)((const char*)S + baddr);
        uint32_t A1 = *(const uint32_t*)((const char*)S + baddr + 4);  // ds_read2
#ifdef HAVE_FDOT2
        fp16x2 wnv = __builtin_amdgcn_cvt_pkrtz(1.0f - wr, wr);        // (1-wr, wr)
        h2 wn = *reinterpret_cast<h2*>(&wnv);
        float rL = __builtin_amdgcn_fdot2(*(h2*)&A0, wn, 0.0f, false); // vert lerp L
        float rR = __builtin_amdgcn_fdot2(*(h2*)&A1, wn, 0.0f, false); // vert lerp R
        accB += rL;
        accD = fmaf(wc, rR - rL, accD);                                // horiz lerp
#else
        __half2 Ah = *reinterpret_cast<__half2*>(&A0);
        __half2 Bh = *reinterpret_cast<__half2*>(&A1);
        float tL = __low2float(Ah), bL = __high2float(Ah);
        float tR = __low2float(Bh), bR = __high2float(Bh);
        float rL = fmaf(wr, bL - tL, tL);
        float rR = fmaf(wr, bR - tR, tR);
        accB += rL;
        accD = fmaf(wc, rR - rL, accD);
#endif
    }
    if (siLo <= siHi)
        unsafeAtomicAdd(&out[((size_t)b * N_ANG + a) * 256 + d], accB + accD);
}

extern "C" void kernel_launch(void* const* d_in, const int* in_sizes, int n_in,
                              void* d_out, int out_size, void* d_ws, size_t ws_size,
                              hipStream_t stream) {
    const float* x      = (const float*)d_in[0];
    const float* angles = (const float*)d_in[1];
    float* out = (float*)d_out;
    (void)hipMemsetAsync(out, 0, (size_t)out_size * sizeof(float), stream);
    // 2048 blocks = 8 batches x 64 angle-groups x 4 quarters; batch = blockIdx%8
    radon_d<<<N_BATCH * (N_ANG / 4) * 4, 1024, 0, stream>>>(x, angles, out);
}